// Round 6
// baseline (262.446 us; speedup 1.0000x reference)
//
#include <hip/hip_runtime.h>
#include <math.h>

#define TT 2048
#define DD 1024
#define HH 16
#define DKK 64
#define BB 4
#define NN 8192  // BB*TT

typedef __bf16 bf16x8 __attribute__((ext_vector_type(8)));
typedef float f32x4 __attribute__((ext_vector_type(4)));
typedef float f32x16 __attribute__((ext_vector_type(16)));

#define QSCALE 0.18033688011112043f   // 0.125 * log2(e)
#define MBIAS -1.4426950e9f           // -1e9 * log2(e)

// round-to-nearest-even f32 -> bf16 bits
__device__ __forceinline__ unsigned short f2bf(float f) {
  unsigned int u = __builtin_bit_cast(unsigned int, f);
  u += 0x7fffu + ((u >> 16) & 1u);
  return (unsigned short)(u >> 16);
}

// v_cvt_pk_bf16_f32: dst.lo16 = bf16(lo), dst.hi16 = bf16(hi)
__device__ __forceinline__ unsigned int cvtpk(float lo, float hi) {
  unsigned int r;
  asm("v_cvt_pk_bf16_f32 %0, %1, %2" : "=v"(r) : "v"(lo), "v"(hi));
  return r;
}

__device__ __forceinline__ void gl_lds16(const void* g, void* s) {
  __builtin_amdgcn_global_load_lds(
      (const __attribute__((address_space(1))) void*)g,
      (__attribute__((address_space(3))) void*)s, 16, 0, 0);
}

// XOR swizzle within a 128B row (used only in the O-transpose epilogue)
#define SWZ(r, byte) ((byte) ^ (((r) & 7) << 4))

// ---------------------------------------------------------------------------
__global__ __launch_bounds__(256) void cast_f32_bf16(
    const float* __restrict__ in, unsigned short* __restrict__ out, int n4) {
  int i = blockIdx.x * blockDim.x + threadIdx.x;
  if (i < n4) {
    float4 v = reinterpret_cast<const float4*>(in)[i];
    ushort4 o;
    o.x = f2bf(v.x); o.y = f2bf(v.y); o.z = f2bf(v.z); o.w = f2bf(v.w);
    reinterpret_cast<ushort4*>(out)[i] = o;
  }
}

// transpose + cast 4 weights (DDxDD f32 row-major [k][n]) -> WT bf16 [n][k]
__global__ __launch_bounds__(256) void wtrans(
    const float* __restrict__ W0, const float* __restrict__ W1,
    const float* __restrict__ W2, const float* __restrict__ W3,
    unsigned short* __restrict__ WT) {
  __shared__ float t[32][33];
  const float* W = (blockIdx.z == 0) ? W0
                   : (blockIdx.z == 1) ? W1
                   : (blockIdx.z == 2) ? W2 : W3;
  unsigned short* O = WT + (size_t)blockIdx.z * DD * DD;
  const int tx = threadIdx.x & 31, ty = threadIdx.x >> 5;
  const int r0 = blockIdx.y * 32, c0 = blockIdx.x * 32;
#pragma unroll
  for (int j = 0; j < 4; ++j)
    t[ty + 8 * j][tx] = W[(size_t)(r0 + ty + 8 * j) * DD + c0 + tx];
  __syncthreads();
#pragma unroll
  for (int j = 0; j < 4; ++j)
    O[(size_t)(c0 + ty + 8 * j) * DD + r0 + tx] = f2bf(t[tx][ty + 8 * j]);
}

// ---------------------------------------------------------------------------
// m97-structure GEMM.  EPI 0: fused QKV (Bw has 3072 rows; scatter to
// fragment-major tiled Qt/Kt/Vt).  EPI 1: out-proj, f32 row-major.
//
// Tiled layouts (element offsets, bf16):
//  Q tile (128 q-rows):  (bh*16 + t>>7)*8192  + (dk>>3)*1024 + (t&127)*8 + (dk&7)
//  K tile (64 kv-rows):  (bh*32 + t>>6)*4096  + (dk>>3)*512 + ((t>>5)&1)*256
//                                             + (t&31)*8 + (dk&7)
//  V tile (64 kv-rows):  (bh*32 + t>>6)*4096  + ((t>>3)&7)*512 + (dk>>5)*256
//                                             + (dk&31)*8 + (t&7)        [V^T]
template <int EPI>
__global__ __launch_bounds__(256) void gemm_m97(
    const unsigned short* __restrict__ A, const unsigned short* __restrict__ Bw,
    const float* __restrict__ b0, const float* __restrict__ b1,
    const float* __restrict__ b2, unsigned short* __restrict__ O0,
    unsigned short* __restrict__ O1, unsigned short* __restrict__ O2,
    float* __restrict__ Of) {
  __shared__ unsigned short As[128 * 32];
  __shared__ unsigned short Bs[128 * 32];
  const int tid = threadIdx.x;
  const int l = tid & 63, w = tid >> 6;
  const int ln = l & 15, kg = l >> 4;
  const int wr = w >> 1, wc = w & 1;
  const int rb = blockIdx.x * 128, cb = blockIdx.y * 128;

  f32x4 acc[4][4];
#pragma unroll
  for (int i = 0; i < 4; ++i)
#pragma unroll
    for (int j = 0; j < 4; ++j)
#pragma unroll
      for (int r = 0; r < 4; ++r) acc[i][j][r] = 0.f;

  const int srow = w * 16 + (l >> 2);
  const int sch = (l & 3) * 16;
  const char* Ag = (const char*)A + (size_t)(rb + srow) * 2048 + sch;
  const char* Bg = (const char*)Bw + (size_t)(cb + srow) * 2048 + sch;
  char* Ad = (char*)As + w * 1024;
  char* Bd = (char*)Bs + w * 1024;

  for (int k0 = 0; k0 < 2048; k0 += 64) {
    __syncthreads();
    gl_lds16(Ag + k0, Ad);
    gl_lds16(Ag + k0 + (size_t)64 * 2048, Ad + 4096);
    gl_lds16(Bg + k0, Bd);
    gl_lds16(Bg + k0 + (size_t)64 * 2048, Bd + 4096);
    __syncthreads();
    bf16x8 af[4], bfv[4];
#pragma unroll
    for (int mi = 0; mi < 4; ++mi)
      af[mi] = *reinterpret_cast<const bf16x8*>(
          (const char*)As + (wr * 64 + mi * 16 + ln) * 64 + kg * 16);
#pragma unroll
    for (int ni = 0; ni < 4; ++ni)
      bfv[ni] = *reinterpret_cast<const bf16x8*>(
          (const char*)Bs + (wc * 64 + ni * 16 + ln) * 64 + kg * 16);
#pragma unroll
    for (int mi = 0; mi < 4; ++mi)
#pragma unroll
      for (int ni = 0; ni < 4; ++ni)
        acc[mi][ni] = __builtin_amdgcn_mfma_f32_16x16x32_bf16(
            af[mi], bfv[ni], acc[mi][ni], 0, 0, 0);
  }

  if constexpr (EPI == 0) {
    const int sel = blockIdx.y >> 3;  // 0=Q 1=K 2=V (uniform per block)
    const float* bias = sel == 0 ? b0 : (sel == 1 ? b1 : b2);
    const float scale = sel == 0 ? QSCALE : 1.0f;
#pragma unroll
    for (int ni = 0; ni < 4; ++ni) {
      const int c3 = cb + wc * 64 + ni * 16 + ln;
      const int c = c3 & 1023, h = (c3 >> 6) & 15, dk = c3 & 63;
      const float bsv = bias[c];
#pragma unroll
      for (int mi = 0; mi < 4; ++mi) {
#pragma unroll
        for (int r = 0; r < 4; ++r) {
          const int rl = rb + wr * 64 + mi * 16 + kg * 4 + r;
          const int b_ = rl >> 11, t = rl & 2047, bh = b_ * HH + h;
          const unsigned short v = f2bf((acc[mi][ni][r] + bsv) * scale);
          if (sel == 0) {
            O0[(size_t)(bh * 16 + (t >> 7)) * 8192 + (dk >> 3) * 1024 +
               (t & 127) * 8 + (dk & 7)] = v;
          } else if (sel == 1) {
            O1[(size_t)(bh * 32 + (t >> 6)) * 4096 + (dk >> 3) * 512 +
               ((t >> 5) & 1) * 256 + (t & 31) * 8 + (dk & 7)] = v;
          } else {
            O2[(size_t)(bh * 32 + (t >> 6)) * 4096 + ((t >> 3) & 7) * 512 +
               (dk >> 5) * 256 + (dk & 31) * 8 + (t & 7)] = v;
          }
        }
      }
    }
  } else {
#pragma unroll
    for (int ni = 0; ni < 4; ++ni) {
      const int cl = cb + wc * 64 + ni * 16 + ln;
      const float bsv = b0[cl];
#pragma unroll
      for (int mi = 0; mi < 4; ++mi)
#pragma unroll
        for (int r = 0; r < 4; ++r) {
          const int rl = rb + wr * 64 + mi * 16 + kg * 4 + r;
          Of[(size_t)rl * DD + cl] = acc[mi][ni][r] + bsv;
        }
    }
  }
}

// ---------------------------------------------------------------------------
// Flash attention v6: v4 + counted-vmcnt 2-deep pipeline (T3+T4).
// Raw s_barrier, no vmcnt(0) drain in the main loop; STAGE issued 2 tiles
// ahead; vmcnt(4) allows next tile's 4 loads to stay in flight.
__global__ __launch_bounds__(256) void attn_v6(
    const unsigned short* __restrict__ Qt, const unsigned short* __restrict__ Kt,
    const unsigned short* __restrict__ Vt, const int* __restrict__ mask,
    unsigned short* __restrict__ Ab) {
  // remap so all 16 q-blocks of one (b,h) share an XCD
  const int id = blockIdx.x + 16 * blockIdx.y;
  const int bh = id & 63, qt = id >> 6;
  const int b = bh >> 4, h = bh & 15;

  __shared__ __align__(16) char lds[40960];
  char* kb = lds;                       // [2][8192] K tiles
  char* vb = lds + 16384;               // [2][8192] V tiles
  float* mbv = (float*)(lds + 32768);   // [2048] mask bias (log2 domain)

  const int tid = threadIdx.x;
  const int l = tid & 63, w = tid >> 6;
  const int ln = l & 31, hi = l >> 5;

  const char* Qtile = (const char*)Qt + (size_t)(bh * 16 + qt) * 16384;
  const char* Ktile = (const char*)Kt + (size_t)bh * 32 * 8192;
  const char* Vtile = (const char*)Vt + (size_t)bh * 32 * 8192;
  const int* mp = mask + b * TT;

  {  // mask bias preload (vectorized)
    const int4* m4 = reinterpret_cast<const int4*>(mp);
    float4* f4 = reinterpret_cast<float4*>(mbv);
    for (int i = tid; i < TT / 4; i += 256) {
      const int4 m = m4[i];
      float4 f;
      f.x = m.x ? 0.f : MBIAS;
      f.y = m.y ? 0.f : MBIAS;
      f.z = m.z ? 0.f : MBIAS;
      f.w = m.w ? 0.f : MBIAS;
      f4[i] = f;
    }
  }

  // Q fragments: direct global->reg (pre-tiled, coalesced)
  const int qrow = w * 32 + ln;
  bf16x8 qf[4];
#pragma unroll
  for (int s = 0; s < 4; ++s)
    qf[s] = *reinterpret_cast<const bf16x8*>(
        Qtile + (size_t)(s * 2 + hi) * 2048 + qrow * 16);

  // staging: wave w covers bytes [w*2048, w*2048+2048) of each 8KB tile
  const int soff = w * 2048 + l * 16;

#define STAGE(bufsel, kt64)                                            \
  {                                                                    \
    const char* ks_ = Ktile + (size_t)(kt64) * 8192 + soff;            \
    const char* vs_ = Vtile + (size_t)(kt64) * 8192 + soff;            \
    char* kd_ = kb + (bufsel) * 8192 + w * 2048;                       \
    char* vd_ = vb + (bufsel) * 8192 + w * 2048;                       \
    gl_lds16(ks_, kd_);                                                \
    gl_lds16(ks_ + 1024, kd_ + 1024);                                  \
    gl_lds16(vs_, vd_);                                                \
    gl_lds16(vs_ + 1024, vd_ + 1024);                                  \
  }

  STAGE(0, 0);
  STAGE(1, 1);
  asm volatile("s_waitcnt lgkmcnt(0)" ::: "memory");  // mask ds_writes done

  f32x16 oc0, oc1;
#pragma unroll
  for (int i = 0; i < 16; ++i) { oc0[i] = 0.f; oc1[i] = 0.f; }
  float l_ = 0.f;

  const char* kfb = kb + hi * 1024 + ln * 16;   // frag base (buf 0)
  const char* vfb = vb + hi * 1024 + ln * 16;

  int cur = 0;
  for (int kt = 0; kt < 32; ++kt) {
    // tile-kt loads landed; tile-(kt+1) loads stay in flight (T4)
    if (kt < 31) {
      asm volatile("s_waitcnt vmcnt(4)" ::: "memory");
    } else {
      asm volatile("s_waitcnt vmcnt(0)" ::: "memory");
    }
    __builtin_amdgcn_s_barrier();        // all waves' stages visible
    __builtin_amdgcn_sched_barrier(0);

    const char* kc = kfb + cur * 8192;
    const char* vc = vfb + cur * 8192;
    const float* mrow = mbv + (kt << 6) + 4 * hi;

    // ---- S^T = K @ Q^T (log2-scaled) ----
    f32x16 sc0, sc1;
#pragma unroll
    for (int i = 0; i < 16; ++i) { sc0[i] = 0.f; sc1[i] = 0.f; }
    __builtin_amdgcn_s_setprio(1);
#pragma unroll
    for (int s = 0; s < 4; ++s) {
      const bf16x8 kf0 = *reinterpret_cast<const bf16x8*>(kc + s * 2048);
      const bf16x8 kf1 = *reinterpret_cast<const bf16x8*>(kc + s * 2048 + 512);
      sc0 = __builtin_amdgcn_mfma_f32_32x32x16_bf16(kf0, qf[s], sc0, 0, 0, 0);
      sc1 = __builtin_amdgcn_mfma_f32_32x32x16_bf16(kf1, qf[s], sc1, 0, 0, 0);
    }
    __builtin_amdgcn_s_setprio(0);

    // ---- P = exp2(S + maskbias) ----
#pragma unroll
    for (int g = 0; g < 4; ++g) {
      const float4 m0 = *reinterpret_cast<const float4*>(mrow + 8 * g);
      const float4 m1 = *reinterpret_cast<const float4*>(mrow + 32 + 8 * g);
      sc0[4 * g + 0] = __builtin_exp2f(sc0[4 * g + 0] + m0.x);
      sc0[4 * g + 1] = __builtin_exp2f(sc0[4 * g + 1] + m0.y);
      sc0[4 * g + 2] = __builtin_exp2f(sc0[4 * g + 2] + m0.z);
      sc0[4 * g + 3] = __builtin_exp2f(sc0[4 * g + 3] + m0.w);
      sc1[4 * g + 0] = __builtin_exp2f(sc1[4 * g + 0] + m1.x);
      sc1[4 * g + 1] = __builtin_exp2f(sc1[4 * g + 1] + m1.y);
      sc1[4 * g + 2] = __builtin_exp2f(sc1[4 * g + 2] + m1.z);
      sc1[4 * g + 3] = __builtin_exp2f(sc1[4 * g + 3] + m1.w);
    }
    // ---- l += sum (pairwise tree, depth 5) ----
    {
      const float ra = ((sc0[0] + sc0[1]) + (sc0[2] + sc0[3])) +
                       ((sc0[4] + sc0[5]) + (sc0[6] + sc0[7]));
      const float rb2 = ((sc0[8] + sc0[9]) + (sc0[10] + sc0[11])) +
                        ((sc0[12] + sc0[13]) + (sc0[14] + sc0[15]));
      const float rc = ((sc1[0] + sc1[1]) + (sc1[2] + sc1[3])) +
                       ((sc1[4] + sc1[5]) + (sc1[6] + sc1[7]));
      const float rd = ((sc1[8] + sc1[9]) + (sc1[10] + sc1[11])) +
                       ((sc1[12] + sc1[13]) + (sc1[14] + sc1[15]));
      float rs = (ra + rb2) + (rc + rd);
      rs += __shfl_xor(rs, 32);
      l_ += rs;
    }

    // ---- P -> bf16 B-frags (cvt_pk + half exchange) ----
    bf16x8 pf[4];
#pragma unroll
    for (int s = 0; s < 4; ++s) {
      const int u = s & 1;
      float p0, p1, p2, p3, p4, p5, p6, p7;
      if ((s >> 1) == 0) {
        p0 = sc0[8 * u + 0]; p1 = sc0[8 * u + 1]; p2 = sc0[8 * u + 2];
        p3 = sc0[8 * u + 3]; p4 = sc0[8 * u + 4]; p5 = sc0[8 * u + 5];
        p6 = sc0[8 * u + 6]; p7 = sc0[8 * u + 7];
      } else {
        p0 = sc1[8 * u + 0]; p1 = sc1[8 * u + 1]; p2 = sc1[8 * u + 2];
        p3 = sc1[8 * u + 3]; p4 = sc1[8 * u + 4]; p5 = sc1[8 * u + 5];
        p6 = sc1[8 * u + 6]; p7 = sc1[8 * u + 7];
      }
      const unsigned int wa0 = cvtpk(p0, p1), wa1 = cvtpk(p2, p3);
      const unsigned int wb0 = cvtpk(p4, p5), wb1 = cvtpk(p6, p7);
      const unsigned int ea0 = (unsigned int)__shfl_xor((int)wa0, 32);
      const unsigned int ea1 = (unsigned int)__shfl_xor((int)wa1, 32);
      const unsigned int eb0 = (unsigned int)__shfl_xor((int)wb0, 32);
      const unsigned int eb1 = (unsigned int)__shfl_xor((int)wb1, 32);
      union { unsigned int u4[4]; bf16x8 v; } pw;
      pw.u4[0] = hi ? eb0 : wa0;
      pw.u4[1] = hi ? eb1 : wa1;
      pw.u4[2] = hi ? wb0 : ea0;
      pw.u4[3] = hi ? wb1 : ea1;
      pf[s] = pw.v;
    }

    // ---- O^T += V^T @ P^T ----
    __builtin_amdgcn_s_setprio(1);
#pragma unroll
    for (int s = 0; s < 4; ++s) {
      const bf16x8 vf0 = *reinterpret_cast<const bf16x8*>(vc + s * 2048);
      const bf16x8 vf1 = *reinterpret_cast<const bf16x8*>(vc + s * 2048 + 512);
      oc0 = __builtin_amdgcn_mfma_f32_32x32x16_bf16(vf0, pf[s], oc0, 0, 0, 0);
      oc1 = __builtin_amdgcn_mfma_f32_32x32x16_bf16(vf1, pf[s], oc1, 0, 0, 0);
    }
    __builtin_amdgcn_s_setprio(0);

    __builtin_amdgcn_sched_barrier(0);
    __builtin_amdgcn_s_barrier();        // everyone done reading buf cur
    if (kt < 30) STAGE(cur, kt + 2);     // issue 2 tiles ahead
    cur ^= 1;
  }
#undef STAGE

  // ---- epilogue: normalize, transpose O through lds, store (B,T,D) ----
  const float inv = 1.0f / l_;
#pragma unroll
  for (int i = 0; i < 16; ++i) { oc0[i] *= inv; oc1[i] *= inv; }
#pragma unroll
  for (int g = 0; g < 4; ++g) {
    const int d0a = 8 * g + 4 * hi;
    uint2 wv;
    wv.x = cvtpk(oc0[4 * g + 0], oc0[4 * g + 1]);
    wv.y = cvtpk(oc0[4 * g + 2], oc0[4 * g + 3]);
    *reinterpret_cast<uint2*>(lds + qrow * 128 + SWZ(qrow, d0a * 2)) = wv;
    uint2 wv1;
    wv1.x = cvtpk(oc1[4 * g + 0], oc1[4 * g + 1]);
    wv1.y = cvtpk(oc1[4 * g + 2], oc1[4 * g + 3]);
    *reinterpret_cast<uint2*>(lds + qrow * 128 + SWZ(qrow, 64 + d0a * 2)) = wv1;
  }
  __syncthreads();
  {
    const int row2 = tid >> 1, halfc = tid & 1;
    char* gout = (char*)Ab + ((size_t)(b * TT + qt * 128 + row2)) * 2048 +
                 h * 128 + halfc * 64;
#pragma unroll
    for (int u2 = 0; u2 < 4; ++u2) {
      const uint4 d4 = *reinterpret_cast<const uint4*>(
          lds + row2 * 128 + SWZ(row2, halfc * 64 + u2 * 16));
      *reinterpret_cast<uint4*>(gout + u2 * 16) = d4;
    }
  }
}

// ---------------------------------------------------------------------------
extern "C" void kernel_launch(void* const* d_in, const int* in_sizes, int n_in,
                              void* d_out, int out_size, void* d_ws,
                              size_t ws_size, hipStream_t stream) {
  const float* x = (const float*)d_in[0];
  const int* attn_mask = (const int*)d_in[1];
  const float* wq = (const float*)d_in[2];
  const float* bq = (const float*)d_in[3];
  const float* wk = (const float*)d_in[4];
  const float* bk = (const float*)d_in[5];
  const float* wv = (const float*)d_in[6];
  const float* bv = (const float*)d_in[7];
  const float* wo = (const float*)d_in[8];
  const float* bo = (const float*)d_in[9];
  float* out = (float*)d_out;

  unsigned short* Xb = (unsigned short*)d_ws;          // NN*DD bf16
  unsigned short* WT = Xb + (size_t)NN * DD;           // 4*DD*DD (q,k,v,o ^T)
  unsigned short* Qt = WT + (size_t)4 * DD * DD;       // tiled Q (pre-scaled)
  unsigned short* Kt = Qt + (size_t)NN * DD;           // tiled K
  unsigned short* Vt = Kt + (size_t)NN * DD;           // tiled V^T
  unsigned short* Ab = Vt + (size_t)NN * DD;           // (B,T,D) bf16

  cast_f32_bf16<<<(NN * DD / 4 + 255) / 256, 256, 0, stream>>>(
      x, Xb, NN * DD / 4);
  wtrans<<<dim3(DD / 32, DD / 32, 4), 256, 0, stream>>>(wq, wk, wv, wo, WT);

  gemm_m97<0><<<dim3(NN / 128, 24), 256, 0, stream>>>(
      Xb, WT, bq, bk, bv, Qt, Kt, Vt, nullptr);
  attn_v6<<<dim3(TT / 128, BB * HH), 256, 0, stream>>>(Qt, Kt, Vt, attn_mask,
                                                       Ab);
  gemm_m97<1><<<dim3(NN / 128, 8), 256, 0, stream>>>(
      Ab, WT + (size_t)3 * DD * DD, bo, nullptr, nullptr, nullptr, nullptr,
      nullptr, out);
}

// Round 7
// 250.126 us; speedup vs baseline: 1.0493x; 1.0493x over previous
//
#include <hip/hip_runtime.h>
#include <math.h>

#define TT 2048
#define DD 1024
#define HH 16
#define DKK 64
#define BB 4
#define NN 8192  // BB*TT

typedef __bf16 bf16x8 __attribute__((ext_vector_type(8)));
typedef float f32x4 __attribute__((ext_vector_type(4)));
typedef float f32x16 __attribute__((ext_vector_type(16)));

#define QSCALE 0.18033688011112043f   // 0.125 * log2(e)
#define MBIAS -1.4426950e9f           // -1e9 * log2(e)

// round-to-nearest-even f32 -> bf16 bits
__device__ __forceinline__ unsigned short f2bf(float f) {
  unsigned int u = __builtin_bit_cast(unsigned int, f);
  u += 0x7fffu + ((u >> 16) & 1u);
  return (unsigned short)(u >> 16);
}

// v_cvt_pk_bf16_f32: dst.lo16 = bf16(lo), dst.hi16 = bf16(hi)
__device__ __forceinline__ unsigned int cvtpk(float lo, float hi) {
  unsigned int r;
  asm("v_cvt_pk_bf16_f32 %0, %1, %2" : "=v"(r) : "v"(lo), "v"(hi));
  return r;
}

__device__ __forceinline__ void gl_lds16(const void* g, void* s) {
  __builtin_amdgcn_global_load_lds(
      (const __attribute__((address_space(1))) void*)g,
      (__attribute__((address_space(3))) void*)s, 16, 0, 0);
}

// XOR swizzle within a 128B row (used only in the O-transpose epilogue)
#define SWZ(r, byte) ((byte) ^ (((r) & 7) << 4))

// ---------------------------------------------------------------------------
__global__ __launch_bounds__(256) void cast_f32_bf16(
    const float* __restrict__ in, unsigned short* __restrict__ out, int n4) {
  int i = blockIdx.x * blockDim.x + threadIdx.x;
  if (i < n4) {
    float4 v = reinterpret_cast<const float4*>(in)[i];
    ushort4 o;
    o.x = f2bf(v.x); o.y = f2bf(v.y); o.z = f2bf(v.z); o.w = f2bf(v.w);
    reinterpret_cast<ushort4*>(out)[i] = o;
  }
}

// transpose + cast 4 weights (DDxDD f32 row-major [k][n]) -> WT bf16 [n][k]
__global__ __launch_bounds__(256) void wtrans(
    const float* __restrict__ W0, const float* __restrict__ W1,
    const float* __restrict__ W2, const float* __restrict__ W3,
    unsigned short* __restrict__ WT) {
  __shared__ float t[32][33];
  const float* W = (blockIdx.z == 0) ? W0
                   : (blockIdx.z == 1) ? W1
                   : (blockIdx.z == 2) ? W2 : W3;
  unsigned short* O = WT + (size_t)blockIdx.z * DD * DD;
  const int tx = threadIdx.x & 31, ty = threadIdx.x >> 5;
  const int r0 = blockIdx.y * 32, c0 = blockIdx.x * 32;
#pragma unroll
  for (int j = 0; j < 4; ++j)
    t[ty + 8 * j][tx] = W[(size_t)(r0 + ty + 8 * j) * DD + c0 + tx];
  __syncthreads();
#pragma unroll
  for (int j = 0; j < 4; ++j)
    O[(size_t)(c0 + ty + 8 * j) * DD + r0 + tx] = f2bf(t[tx][ty + 8 * j]);
}

// ---------------------------------------------------------------------------
// m97-structure GEMM.  EPI 0: fused QKV (Bw has 3072 rows; scatter to
// fragment-major tiled Qt/Kt/Vt).  EPI 1: out-proj, f32 row-major.
template <int EPI>
__global__ __launch_bounds__(256) void gemm_m97(
    const unsigned short* __restrict__ A, const unsigned short* __restrict__ Bw,
    const float* __restrict__ b0, const float* __restrict__ b1,
    const float* __restrict__ b2, unsigned short* __restrict__ O0,
    unsigned short* __restrict__ O1, unsigned short* __restrict__ O2,
    float* __restrict__ Of) {
  __shared__ unsigned short As[128 * 32];
  __shared__ unsigned short Bs[128 * 32];
  const int tid = threadIdx.x;
  const int l = tid & 63, w = tid >> 6;
  const int ln = l & 15, kg = l >> 4;
  const int wr = w >> 1, wc = w & 1;
  const int rb = blockIdx.x * 128, cb = blockIdx.y * 128;

  f32x4 acc[4][4];
#pragma unroll
  for (int i = 0; i < 4; ++i)
#pragma unroll
    for (int j = 0; j < 4; ++j)
#pragma unroll
      for (int r = 0; r < 4; ++r) acc[i][j][r] = 0.f;

  const int srow = w * 16 + (l >> 2);
  const int sch = (l & 3) * 16;
  const char* Ag = (const char*)A + (size_t)(rb + srow) * 2048 + sch;
  const char* Bg = (const char*)Bw + (size_t)(cb + srow) * 2048 + sch;
  char* Ad = (char*)As + w * 1024;
  char* Bd = (char*)Bs + w * 1024;

  for (int k0 = 0; k0 < 2048; k0 += 64) {
    __syncthreads();
    gl_lds16(Ag + k0, Ad);
    gl_lds16(Ag + k0 + (size_t)64 * 2048, Ad + 4096);
    gl_lds16(Bg + k0, Bd);
    gl_lds16(Bg + k0 + (size_t)64 * 2048, Bd + 4096);
    __syncthreads();
    bf16x8 af[4], bfv[4];
#pragma unroll
    for (int mi = 0; mi < 4; ++mi)
      af[mi] = *reinterpret_cast<const bf16x8*>(
          (const char*)As + (wr * 64 + mi * 16 + ln) * 64 + kg * 16);
#pragma unroll
    for (int ni = 0; ni < 4; ++ni)
      bfv[ni] = *reinterpret_cast<const bf16x8*>(
          (const char*)Bs + (wc * 64 + ni * 16 + ln) * 64 + kg * 16);
#pragma unroll
    for (int mi = 0; mi < 4; ++mi)
#pragma unroll
      for (int ni = 0; ni < 4; ++ni)
        acc[mi][ni] = __builtin_amdgcn_mfma_f32_16x16x32_bf16(
            af[mi], bfv[ni], acc[mi][ni], 0, 0, 0);
  }

  if constexpr (EPI == 0) {
    const int sel = blockIdx.y >> 3;  // 0=Q 1=K 2=V (uniform per block)
    const float* bias = sel == 0 ? b0 : (sel == 1 ? b1 : b2);
    const float scale = sel == 0 ? QSCALE : 1.0f;
#pragma unroll
    for (int ni = 0; ni < 4; ++ni) {
      const int c3 = cb + wc * 64 + ni * 16 + ln;
      const int c = c3 & 1023, h = (c3 >> 6) & 15, dk = c3 & 63;
      const float bsv = bias[c];
#pragma unroll
      for (int mi = 0; mi < 4; ++mi) {
#pragma unroll
        for (int r = 0; r < 4; ++r) {
          const int rl = rb + wr * 64 + mi * 16 + kg * 4 + r;
          const int b_ = rl >> 11, t = rl & 2047, bh = b_ * HH + h;
          const unsigned short v = f2bf((acc[mi][ni][r] + bsv) * scale);
          if (sel == 0) {
            O0[(size_t)(bh * 16 + (t >> 7)) * 8192 + (dk >> 3) * 1024 +
               (t & 127) * 8 + (dk & 7)] = v;
          } else if (sel == 1) {
            O1[(size_t)(bh * 32 + (t >> 6)) * 4096 + (dk >> 3) * 512 +
               ((t >> 5) & 1) * 256 + (t & 31) * 8 + (dk & 7)] = v;
          } else {
            O2[(size_t)(bh * 32 + (t >> 6)) * 4096 + ((t >> 3) & 7) * 512 +
               (dk >> 5) * 256 + (dk & 31) * 8 + (t & 7)] = v;
          }
        }
      }
    }
  } else {
#pragma unroll
    for (int ni = 0; ni < 4; ++ni) {
      const int cl = cb + wc * 64 + ni * 16 + ln;
      const float bsv = b0[cl];
#pragma unroll
      for (int mi = 0; mi < 4; ++mi)
#pragma unroll
        for (int r = 0; r < 4; ++r) {
          const int rl = rb + wr * 64 + mi * 16 + kg * 4 + r;
          Of[(size_t)rl * DD + cl] = acc[mi][ni][r] + bsv;
        }
    }
  }
}

// ---------------------------------------------------------------------------
// attn v7 tile body.  PF=1: prefetch K(kt+1) into kN and bias(kt+1) into sc.
template <int PF>
__device__ __forceinline__ void attn_tile(
    int kt, const char* Kbase, const char* Vbase, const float* mbv, int foff,
    int hi, const bf16x8 (&qf)[4], bf16x8 (&kA)[8], f32x16& sc0, f32x16& sc1,
    f32x16& oc0, f32x16& oc1, float& l_) {
  // V(kt): direct global->reg, consumed by PV ~300cy later
  bf16x8 vf[8];
#pragma unroll
  for (int s = 0; s < 4; ++s) {
    vf[2 * s] = *reinterpret_cast<const bf16x8*>(
        Vbase + (size_t)kt * 8192 + s * 2048 + foff);
    vf[2 * s + 1] = *reinterpret_cast<const bf16x8*>(
        Vbase + (size_t)kt * 8192 + s * 2048 + 512 + foff);
  }
  // K(kt+1): prefetch one tile ahead
  bf16x8 kN[8];
  if (PF) {
#pragma unroll
    for (int s = 0; s < 4; ++s) {
      kN[2 * s] = *reinterpret_cast<const bf16x8*>(
          Kbase + (size_t)(kt + 1) * 8192 + s * 2048 + foff);
      kN[2 * s + 1] = *reinterpret_cast<const bf16x8*>(
          Kbase + (size_t)(kt + 1) * 8192 + s * 2048 + 512 + foff);
    }
  }

  // ---- S^T = K @ Q^T + maskbias (bias pre-loaded as C) ----
  __builtin_amdgcn_s_setprio(1);
#pragma unroll
  for (int s = 0; s < 4; ++s) {
    sc0 = __builtin_amdgcn_mfma_f32_32x32x16_bf16(kA[2 * s], qf[s], sc0, 0, 0, 0);
    sc1 = __builtin_amdgcn_mfma_f32_32x32x16_bf16(kA[2 * s + 1], qf[s], sc1, 0, 0, 0);
  }
  __builtin_amdgcn_s_setprio(0);

  // ---- P = exp2(S) ----
#pragma unroll
  for (int i = 0; i < 16; ++i) sc0[i] = __builtin_exp2f(sc0[i]);
#pragma unroll
  for (int i = 0; i < 16; ++i) sc1[i] = __builtin_exp2f(sc1[i]);
  // ---- l += sum (pairwise tree) ----
  {
    const float ra = ((sc0[0] + sc0[1]) + (sc0[2] + sc0[3])) +
                     ((sc0[4] + sc0[5]) + (sc0[6] + sc0[7]));
    const float rb2 = ((sc0[8] + sc0[9]) + (sc0[10] + sc0[11])) +
                      ((sc0[12] + sc0[13]) + (sc0[14] + sc0[15]));
    const float rc = ((sc1[0] + sc1[1]) + (sc1[2] + sc1[3])) +
                     ((sc1[4] + sc1[5]) + (sc1[6] + sc1[7]));
    const float rd = ((sc1[8] + sc1[9]) + (sc1[10] + sc1[11])) +
                     ((sc1[12] + sc1[13]) + (sc1[14] + sc1[15]));
    float rs = (ra + rb2) + (rc + rd);
    rs += __shfl_xor(rs, 32);
    l_ += rs;
  }

  // ---- P -> bf16 B-frags (cvt_pk + half exchange) ----
  bf16x8 pf[4];
#pragma unroll
  for (int s = 0; s < 4; ++s) {
    const int u = s & 1;
    float p0, p1, p2, p3, p4, p5, p6, p7;
    if ((s >> 1) == 0) {
      p0 = sc0[8 * u + 0]; p1 = sc0[8 * u + 1]; p2 = sc0[8 * u + 2];
      p3 = sc0[8 * u + 3]; p4 = sc0[8 * u + 4]; p5 = sc0[8 * u + 5];
      p6 = sc0[8 * u + 6]; p7 = sc0[8 * u + 7];
    } else {
      p0 = sc1[8 * u + 0]; p1 = sc1[8 * u + 1]; p2 = sc1[8 * u + 2];
      p3 = sc1[8 * u + 3]; p4 = sc1[8 * u + 4]; p5 = sc1[8 * u + 5];
      p6 = sc1[8 * u + 6]; p7 = sc1[8 * u + 7];
    }
    const unsigned int wa0 = cvtpk(p0, p1), wa1 = cvtpk(p2, p3);
    const unsigned int wb0 = cvtpk(p4, p5), wb1 = cvtpk(p6, p7);
    const unsigned int ea0 = (unsigned int)__shfl_xor((int)wa0, 32);
    const unsigned int ea1 = (unsigned int)__shfl_xor((int)wa1, 32);
    const unsigned int eb0 = (unsigned int)__shfl_xor((int)wb0, 32);
    const unsigned int eb1 = (unsigned int)__shfl_xor((int)wb1, 32);
    union { unsigned int u4[4]; bf16x8 v; } pw;
    pw.u4[0] = hi ? eb0 : wa0;
    pw.u4[1] = hi ? eb1 : wa1;
    pw.u4[2] = hi ? wb0 : ea0;
    pw.u4[3] = hi ? wb1 : ea1;
    pf[s] = pw.v;
  }

  // ---- bias(kt+1) -> sc (C-init for next tile; sc is dead here) ----
  if (PF) {
    const float* mrow = mbv + ((kt + 1) << 6) + 4 * hi;
#pragma unroll
    for (int g = 0; g < 4; ++g) {
      const float4 m0 = *reinterpret_cast<const float4*>(mrow + 8 * g);
      const float4 m1 = *reinterpret_cast<const float4*>(mrow + 32 + 8 * g);
      sc0[4 * g + 0] = m0.x; sc0[4 * g + 1] = m0.y;
      sc0[4 * g + 2] = m0.z; sc0[4 * g + 3] = m0.w;
      sc1[4 * g + 0] = m1.x; sc1[4 * g + 1] = m1.y;
      sc1[4 * g + 2] = m1.z; sc1[4 * g + 3] = m1.w;
    }
  }

  // ---- O^T += V^T @ P^T ----
  __builtin_amdgcn_s_setprio(1);
#pragma unroll
  for (int s = 0; s < 4; ++s) {
    oc0 = __builtin_amdgcn_mfma_f32_32x32x16_bf16(vf[2 * s], pf[s], oc0, 0, 0, 0);
    oc1 = __builtin_amdgcn_mfma_f32_32x32x16_bf16(vf[2 * s + 1], pf[s], oc1, 0, 0, 0);
  }
  __builtin_amdgcn_s_setprio(0);

  if (PF) {
#pragma unroll
    for (int i = 0; i < 8; ++i) kA[i] = kN[i];
  }
}

// ---------------------------------------------------------------------------
// Flash attention v7: barrier-free register-direct K/V (no LDS staging).
// Waves run fully decoupled; K prefetched 1 tile ahead in regs; V issued at
// tile top; mask bias in LDS (read-only after one pre-loop barrier) feeds the
// MFMA C operand directly.  L1/XCD-local-L2 serve the K/V reuse.
__global__ __launch_bounds__(256) void attn_v7(
    const unsigned short* __restrict__ Qt, const unsigned short* __restrict__ Kt,
    const unsigned short* __restrict__ Vt, const int* __restrict__ mask,
    unsigned short* __restrict__ Ab) {
  // remap: blocks of one bh land on one XCD (dispatch_idx % 8 == bh % 8)
  const int id = blockIdx.x + 16 * blockIdx.y;
  const int bh = id & 63, qt = id >> 6;
  const int b = bh >> 4, h = bh & 15;

  __shared__ __align__(16) char lds[16384];  // mask bias, then O transpose
  float* mbv = (float*)lds;

  const int tid = threadIdx.x;
  const int l = tid & 63, w = tid >> 6;
  const int ln = l & 31, hi = l >> 5;

  const char* Qtile = (const char*)Qt + (size_t)(bh * 16 + qt) * 16384;
  const char* Kbase = (const char*)Kt + (size_t)bh * 32 * 8192;
  const char* Vbase = (const char*)Vt + (size_t)bh * 32 * 8192;
  const int* mp = mask + b * TT;

  {  // mask -> log2-domain additive bias, vectorized
    const int4* m4 = reinterpret_cast<const int4*>(mp);
    float4* f4 = reinterpret_cast<float4*>(mbv);
    for (int i = tid; i < TT / 4; i += 256) {
      const int4 m = m4[i];
      float4 f;
      f.x = m.x ? 0.f : MBIAS;
      f.y = m.y ? 0.f : MBIAS;
      f.z = m.z ? 0.f : MBIAS;
      f.w = m.w ? 0.f : MBIAS;
      f4[i] = f;
    }
  }
  __syncthreads();  // mbv visible to all waves (only barrier before epilogue)

  // Q fragments: direct global->reg
  const int qrow = w * 32 + ln;
  bf16x8 qf[4];
#pragma unroll
  for (int s = 0; s < 4; ++s)
    qf[s] = *reinterpret_cast<const bf16x8*>(
        Qtile + (size_t)(s * 2 + hi) * 2048 + qrow * 16);

  const int foff = hi * 1024 + ln * 16;

  // prologue: K(0) + bias(0)
  bf16x8 kA[8];
#pragma unroll
  for (int s = 0; s < 4; ++s) {
    kA[2 * s] = *reinterpret_cast<const bf16x8*>(Kbase + s * 2048 + foff);
    kA[2 * s + 1] =
        *reinterpret_cast<const bf16x8*>(Kbase + s * 2048 + 512 + foff);
  }
  f32x16 sc0, sc1;
  {
    const float* mrow = mbv + 4 * hi;
#pragma unroll
    for (int g = 0; g < 4; ++g) {
      const float4 m0 = *reinterpret_cast<const float4*>(mrow + 8 * g);
      const float4 m1 = *reinterpret_cast<const float4*>(mrow + 32 + 8 * g);
      sc0[4 * g + 0] = m0.x; sc0[4 * g + 1] = m0.y;
      sc0[4 * g + 2] = m0.z; sc0[4 * g + 3] = m0.w;
      sc1[4 * g + 0] = m1.x; sc1[4 * g + 1] = m1.y;
      sc1[4 * g + 2] = m1.z; sc1[4 * g + 3] = m1.w;
    }
  }

  f32x16 oc0, oc1;
#pragma unroll
  for (int i = 0; i < 16; ++i) { oc0[i] = 0.f; oc1[i] = 0.f; }
  float l_ = 0.f;

  for (int kt = 0; kt < 31; ++kt)
    attn_tile<1>(kt, Kbase, Vbase, mbv, foff, hi, qf, kA, sc0, sc1, oc0, oc1,
                 l_);
  attn_tile<0>(31, Kbase, Vbase, mbv, foff, hi, qf, kA, sc0, sc1, oc0, oc1,
               l_);

  // ---- epilogue: normalize, transpose O through lds, store (B,T,D) ----
  __syncthreads();  // all waves done with mbv; lds reused for O
  const float inv = 1.0f / l_;
#pragma unroll
  for (int i = 0; i < 16; ++i) { oc0[i] *= inv; oc1[i] *= inv; }
#pragma unroll
  for (int g = 0; g < 4; ++g) {
    const int d0a = 8 * g + 4 * hi;
    uint2 wv;
    wv.x = cvtpk(oc0[4 * g + 0], oc0[4 * g + 1]);
    wv.y = cvtpk(oc0[4 * g + 2], oc0[4 * g + 3]);
    *reinterpret_cast<uint2*>(lds + qrow * 128 + SWZ(qrow, d0a * 2)) = wv;
    uint2 wv1;
    wv1.x = cvtpk(oc1[4 * g + 0], oc1[4 * g + 1]);
    wv1.y = cvtpk(oc1[4 * g + 2], oc1[4 * g + 3]);
    *reinterpret_cast<uint2*>(lds + qrow * 128 + SWZ(qrow, 64 + d0a * 2)) = wv1;
  }
  __syncthreads();
  {
    const int row2 = tid >> 1, halfc = tid & 1;
    char* gout = (char*)Ab + ((size_t)(b * TT + qt * 128 + row2)) * 2048 +
                 h * 128 + halfc * 64;
#pragma unroll
    for (int u2 = 0; u2 < 4; ++u2) {
      const uint4 d4 = *reinterpret_cast<const uint4*>(
          lds + row2 * 128 + SWZ(row2, halfc * 64 + u2 * 16));
      *reinterpret_cast<uint4*>(gout + u2 * 16) = d4;
    }
  }
}

// ---------------------------------------------------------------------------
extern "C" void kernel_launch(void* const* d_in, const int* in_sizes, int n_in,
                              void* d_out, int out_size, void* d_ws,
                              size_t ws_size, hipStream_t stream) {
  const float* x = (const float*)d_in[0];
  const int* attn_mask = (const int*)d_in[1];
  const float* wq = (const float*)d_in[2];
  const float* bq = (const float*)d_in[3];
  const float* wk = (const float*)d_in[4];
  const float* bk = (const float*)d_in[5];
  const float* wv = (const float*)d_in[6];
  const float* bv = (const float*)d_in[7];
  const float* wo = (const float*)d_in[8];
  const float* bo = (const float*)d_in[9];
  float* out = (float*)d_out;

  unsigned short* Xb = (unsigned short*)d_ws;          // NN*DD bf16
  unsigned short* WT = Xb + (size_t)NN * DD;           // 4*DD*DD (q,k,v,o ^T)
  unsigned short* Qt = WT + (size_t)4 * DD * DD;       // tiled Q (pre-scaled)
  unsigned short* Kt = Qt + (size_t)NN * DD;           // tiled K
  unsigned short* Vt = Kt + (size_t)NN * DD;           // tiled V^T
  unsigned short* Ab = Vt + (size_t)NN * DD;           // (B,T,D) bf16

  cast_f32_bf16<<<(NN * DD / 4 + 255) / 256, 256, 0, stream>>>(
      x, Xb, NN * DD / 4);
  wtrans<<<dim3(DD / 32, DD / 32, 4), 256, 0, stream>>>(wq, wk, wv, wo, WT);

  gemm_m97<0><<<dim3(NN / 128, 24), 256, 0, stream>>>(
      Xb, WT, bq, bk, bv, Qt, Kt, Vt, nullptr);
  attn_v7<<<dim3(TT / 128, BB * HH), 256, 0, stream>>>(Qt, Kt, Vt, attn_mask,
                                                       Ab);
  gemm_m97<1><<<dim3(NN / 128, 8), 256, 0, stream>>>(
      Ab, WT + (size_t)3 * DD * DD, bo, nullptr, nullptr, nullptr, nullptr,
      nullptr, out);
}